// Round 8
// baseline (363.908 us; speedup 1.0000x reference)
//
#include <hip/hip_runtime.h>

#define D 200
#define RRELU_SLOPE 0.22916666666666666f
#define STRIDE 96              // padded per-node edge capacity (P[deg>96] ~ 1e-41)
#define PAD 8                  // edge-loop round size
#define EPT 8                  // edges per scatter thread (ILP)

typedef unsigned short u16;
typedef unsigned int u32;

using bf16x8 = __attribute__((ext_vector_type(8))) short;
using f32x4  = __attribute__((ext_vector_type(4))) float;
using f32x2  = __attribute__((ext_vector_type(2))) float;

__device__ __forceinline__ float rrelu(float x) {
    return x >= 0.0f ? x : x * RRELU_SLOPE;
}
__device__ __forceinline__ float bf2f(u32 u) {
    union { u32 i; float f; } c; c.i = u << 16; return c.f;
}
__device__ __forceinline__ u32 f2bf(float f) {
    union { float f; u32 i; } c; c.f = f;
    return (c.i + 0x7fffu + ((c.i >> 16) & 1u)) >> 16;
}
__device__ __forceinline__ u32 pack2(float x, float y) {
    return f2bf(x) | (f2bf(y) << 16);
}
__device__ __forceinline__ void gll16(const void* g, void* l) {
    __builtin_amdgcn_global_load_lds((const __attribute__((address_space(1))) void*)g,
                                     (__attribute__((address_space(3))) void*)l,
                                     16, 0, 0);
}

// unpack one u32 (2 bf16 = adjacent channels) and packed-accumulate into f32x2
// (compiler emits v_pk_add_f32 on gfx950).
__device__ __forceinline__ void accw(u32 w, f32x2& acc) {
    union { u32 i; float f; } lo, hi;
    lo.i = w << 16;
    hi.i = w & 0xffff0000u;
    f32x2 t; t[0] = lo.f; t[1] = hi.f;
    acc += t;
}
// unpack uint4 (8 bf16) into 4 packed accumulators
__device__ __forceinline__ void accq(uint4 q, f32x2* a) {
    accw(q.x, a[0]); accw(q.y, a[1]); accw(q.z, a[2]); accw(q.w, a[3]);
}

// ---- fused front kernel: scatter + prep (relb/Bt/dummies) + h0 gather ----
// Scatter blocks FIRST (long pole overlaps the rest). ep stores are
// NON-TEMPORAL: random 4B stores thrash L2 via read-for-ownership; streaming
// them past L2 removes the fetch+writeback amplification (R7 post-mortem).

__global__ void front_k(const float* __restrict__ rel, const float* __restrict__ Wn,
                        const float* __restrict__ Wl, u16* __restrict__ relb,
                        u16* __restrict__ Bt, u16* __restrict__ hb0d,
                        u16* __restrict__ hb1d, int* __restrict__ noin_cnt,
                        const int* __restrict__ dst, const int* __restrict__ src,
                        const int* __restrict__ etype, int* __restrict__ cnt,
                        u32* __restrict__ ep, int E,
                        const float* __restrict__ init, const int* __restrict__ nid,
                        u16* __restrict__ hb, int N,
                        int prepB, int scatB) {
    int b = blockIdx.x;
    if (b < scatB) {
        int base = (b * blockDim.x + threadIdx.x) * EPT;
        if (base + EPT <= E) {
            int4 d0 = *(const int4*)(dst + base);
            int4 d1 = *(const int4*)(dst + base + 4);
            int4 s0 = *(const int4*)(src + base);
            int4 s1 = *(const int4*)(src + base + 4);
            int4 t0 = *(const int4*)(etype + base);
            int4 t1 = *(const int4*)(etype + base + 4);
            int dd[8] = {d0.x, d0.y, d0.z, d0.w, d1.x, d1.y, d1.z, d1.w};
            int ss[8] = {s0.x, s0.y, s0.z, s0.w, s1.x, s1.y, s1.z, s1.w};
            int tt[8] = {t0.x, t0.y, t0.z, t0.w, t1.x, t1.y, t1.z, t1.w};
            int cc[8];
#pragma unroll
            for (int j = 0; j < 8; ++j) cc[j] = atomicAdd(&cnt[dd[j]], 1);
#pragma unroll
            for (int j = 0; j < 8; ++j)
                if (cc[j] < STRIDE)
                    __builtin_nontemporal_store(
                        (u32)ss[j] | ((u32)tt[j] << 17),
                        &ep[(size_t)dd[j] * STRIDE + cc[j]]);
        } else {
            for (int j = 0; j < EPT; ++j) {
                int e = base + j;
                if (e < E) {
                    int d = dst[e];
                    int c = atomicAdd(&cnt[d], 1);
                    if (c < STRIDE)
                        __builtin_nontemporal_store(
                            (u32)src[e] | ((u32)etype[e] << 17),
                            &ep[(size_t)d * STRIDE + c]);
                }
            }
        }
    } else if (b < scatB + prepB) {
        int i = (b - scatB) * blockDim.x + threadIdx.x;
        if (i == 0) *noin_cnt = 0;
        if (i < 200) { hb0d[i] = 0; hb1d[i] = 0; }
        if (i < 100200) relb[i] = (i < 100000) ? (u16)f2bf(rel[i]) : (u16)0;
        if (i < 2 * 256 * 416) {
            int l = i / (256 * 416);
            int rem = i % (256 * 416);
            int c = rem / 416;
            int k = rem % 416;
            float v = 0.0f;
            if (c < 200 && k < 400)
                v = (k < 200) ? Wn[(size_t)l * 40000 + k * 200 + c]
                              : Wl[(size_t)l * 40000 + (k - 200) * 200 + c];
            Bt[i] = (u16)f2bf(v);
        }
    } else {
        int lane = threadIdx.x & 63;
        int v = (b - scatB - prepB) * 4 + (threadIdx.x >> 6);
        if (v >= N || lane >= 50) return;
        float4 f = *(const float4*)(init + (size_t)nid[v] * D + lane * 4);
        uint2 o;
        o.x = pack2(f.x, f.y);
        o.y = pack2(f.z, f.w);
        *(uint2*)(hb + (size_t)v * D + lane * 4) = o;
    }
}

// pad each node's segment with dummies up to a multiple of PAD; build noin
__global__ void pad_k(const int* __restrict__ cnt, u32* __restrict__ ep, u32 dummy,
                      int* __restrict__ noin, int* __restrict__ noin_cnt, int N) {
    int v = blockIdx.x * blockDim.x + threadIdx.x;
    if (v >= N) return;
    int c = cnt[v];
    if (c > STRIDE) c = STRIDE;
    if (c == 0) noin[atomicAdd(noin_cnt, 1)] = v;
    int e = (c + PAD - 1) & ~(PAD - 1);
    for (int i = c; i < e; ++i) ep[(size_t)v * STRIDE + i] = dummy;
}

// ---- layer-0 gather: aggb = bf16((Σh + Σrel)*norm), relsumb = bf16(Σrel)
// Two nodes per wave (half-wave each, 25 lanes x uint4). Depth-1 software
// pipeline (verified neutral-to-equal vs compiler schedule; kept).

__global__ __launch_bounds__(256) void gagg0_k(
        const u16* __restrict__ hb, const u16* __restrict__ relb,
        const u32* __restrict__ ep, const int* __restrict__ cnt,
        const float* __restrict__ norm,
        u16* __restrict__ aggb, u16* __restrict__ relsumb, int N, u32 dummy) {
    int lane = threadIdx.x & 63;
    int wave = threadIdx.x >> 6;
    int li = lane & 31;
    int v = blockIdx.x * 8 + wave * 2 + (lane >> 5);
    if (v >= N || li >= 25) return;
    size_t lo = (size_t)li * 8;
    const u16* hbL = hb + lo;
    const u16* rbL = relb + lo;
    int c = cnt[v];
    if (c > STRIDE) c = STRIDE;
    int rv = (c + PAD - 1) >> 3;
    const u32* pp = ep + (size_t)v * STRIDE;
    f32x2 a[4] = {}, rr[4] = {};
    u32 p[8];
    uint4 qh[8];
#pragma unroll
    for (int j = 0; j < 8; ++j) p[j] = (rv > 0) ? pp[j] : dummy;
#pragma unroll
    for (int j = 0; j < 8; ++j)
        qh[j] = *(const uint4*)(hbL + (size_t)(p[j] & 0x1FFFFu) * D);
    for (int r = 0; r < rv; ++r) {
        u32 pn[8];
#pragma unroll
        for (int j = 0; j < 8; ++j)
            pn[j] = (r + 1 < rv) ? pp[(size_t)(r + 1) * 8 + j] : dummy;
        uint4 qr[8];
#pragma unroll
        for (int j = 0; j < 8; ++j)
            qr[j] = *(const uint4*)(rbL + (size_t)((p[j] >> 17) & 0x3FFu) * D);
#pragma unroll
        for (int j = 0; j < 8; ++j) accq(qh[j], a);
#pragma unroll
        for (int j = 0; j < 8; ++j)
            qh[j] = *(const uint4*)(hbL + (size_t)(pn[j] & 0x1FFFFu) * D);
#pragma unroll
        for (int j = 0; j < 8; ++j) accq(qr[j], rr);
#pragma unroll
        for (int j = 0; j < 8; ++j) p[j] = pn[j];
    }
    uint4 rs;
    rs.x = pack2(rr[0][0], rr[0][1]); rs.y = pack2(rr[1][0], rr[1][1]);
    rs.z = pack2(rr[2][0], rr[2][1]); rs.w = pack2(rr[3][0], rr[3][1]);
    *(uint4*)(relsumb + (size_t)v * D + lo) = rs;
    float nv = norm[v];
    uint4 o;
    o.x = pack2((a[0][0] + rr[0][0]) * nv, (a[0][1] + rr[0][1]) * nv);
    o.y = pack2((a[1][0] + rr[1][0]) * nv, (a[1][1] + rr[1][1]) * nv);
    o.z = pack2((a[2][0] + rr[2][0]) * nv, (a[2][1] + rr[2][1]) * nv);
    o.w = pack2((a[3][0] + rr[3][0]) * nv, (a[3][1] + rr[3][1]) * nv);
    *(uint4*)(aggb + (size_t)v * D + lo) = o;
}

// ---- layer-1 gather: aggb = bf16((Σh + relsumb)*norm) -------------------

__global__ __launch_bounds__(256) void gagg1_k(
        const u16* __restrict__ hb, const u32* __restrict__ ep,
        const int* __restrict__ cnt, const float* __restrict__ norm,
        const u16* __restrict__ addb, u16* __restrict__ outb, int N, u32 dummy) {
    int lane = threadIdx.x & 63;
    int wave = threadIdx.x >> 6;
    int li = lane & 31;
    int v = blockIdx.x * 8 + wave * 2 + (lane >> 5);
    if (v >= N || li >= 25) return;
    size_t lo = (size_t)li * 8;
    const u16* hbL = hb + lo;
    int c = cnt[v];
    if (c > STRIDE) c = STRIDE;
    int rv = (c + PAD - 1) >> 3;
    const u32* pp = ep + (size_t)v * STRIDE;
    f32x2 a[4] = {};
    u32 p[8];
    uint4 qh[8];
#pragma unroll
    for (int j = 0; j < 8; ++j) p[j] = (rv > 0) ? pp[j] : dummy;
#pragma unroll
    for (int j = 0; j < 8; ++j)
        qh[j] = *(const uint4*)(hbL + (size_t)(p[j] & 0x1FFFFu) * D);
    for (int r = 0; r < rv; ++r) {
        u32 pn[8];
#pragma unroll
        for (int j = 0; j < 8; ++j)
            pn[j] = (r + 1 < rv) ? pp[(size_t)(r + 1) * 8 + j] : dummy;
#pragma unroll
        for (int j = 0; j < 8; ++j) accq(qh[j], a);
#pragma unroll
        for (int j = 0; j < 8; ++j)
            qh[j] = *(const uint4*)(hbL + (size_t)(pn[j] & 0x1FFFFu) * D);
#pragma unroll
        for (int j = 0; j < 8; ++j) p[j] = pn[j];
    }
    {
        uint4 q = *(const uint4*)(addb + (size_t)v * D + lo);
        accq(q, a);
    }
    float nv = norm[v];
    uint4 o;
    o.x = pack2(a[0][0] * nv, a[0][1] * nv);
    o.y = pack2(a[1][0] * nv, a[1][1] * nv);
    o.z = pack2(a[2][0] * nv, a[2][1] * nv);
    o.w = pack2(a[3][0] * nv, a[3][1] * nv);
    *(uint4*)(outb + (size_t)v * D + lo) = o;
}

// ---- MFMA GEMM: out = rrelu([aggb | hb] @ Bt^T) -------------------------
// BM=64 x BN=256 (all cols in one pass; A read once). Double-buffered LDS,
// 2-phase pipeline: STAGE(t+1) issued BEFORE compute(t); ONE barrier/K-step.

__global__ __launch_bounds__(256) void gemm_k(
        const u16* __restrict__ Aagg, const u16* __restrict__ Ah,
        const u16* __restrict__ Bt,
        float* __restrict__ outF, u16* __restrict__ outB, int M) {
    __shared__ __align__(16) u16 As[2][64 * 32];     // 2 x 4 KB
    __shared__ __align__(16) u16 Bs[2][256 * 32];    // 2 x 16 KB
    int tid = threadIdx.x;
    int lane = tid & 63;
    int wave = tid >> 6;
    int rowBase = blockIdx.x * 64;
    int m = lane & 15;
    int kq = (lane >> 4) * 8;

    int srow = tid >> 2;            // 0..63 (A-row / B-col within chunk)
    int kg = (tid & 3) * 8;
    size_t aRow = (size_t)(rowBase + srow);

    f32x4 acc[4][4] = {};

    auto stage = [&](int buf, int k0) {
        int k = k0 + kg;
        const u16* gA = (k < 200) ? Aagg + aRow * D + k
                                  : Ah + aRow * D + (k - 200);
        gll16(gA, &As[buf][0] + wave * 512);
#pragma unroll
        for (int p = 0; p < 4; ++p) {
            const u16* gB = Bt + (size_t)(p * 64 + srow) * 416 + k;
            gll16(gB, &Bs[buf][0] + p * 2048 + wave * 512);
        }
    };

    stage(0, 0);
    __syncthreads();

    int cur = 0;
    for (int t = 0; t < 13; ++t) {
        if (t < 12) stage(cur ^ 1, (t + 1) * 32);   // prefetch next tile

        const u16* A = &As[cur][0];
        const u16* B = &Bs[cur][0];
        bf16x8 a0 = *(const bf16x8*)(A + (m) * 32 + kq);
        bf16x8 a1 = *(const bf16x8*)(A + (16 + m) * 32 + kq);
        bf16x8 a2 = *(const bf16x8*)(A + (32 + m) * 32 + kq);
        bf16x8 a3 = *(const bf16x8*)(A + (48 + m) * 32 + kq);
        int wc = wave * 64;
        bf16x8 b0 = *(const bf16x8*)(B + (wc + m) * 32 + kq);
        bf16x8 b1 = *(const bf16x8*)(B + (wc + 16 + m) * 32 + kq);
        bf16x8 b2 = *(const bf16x8*)(B + (wc + 32 + m) * 32 + kq);
        bf16x8 b3 = *(const bf16x8*)(B + (wc + 48 + m) * 32 + kq);
        acc[0][0] = __builtin_amdgcn_mfma_f32_16x16x32_bf16(a0, b0, acc[0][0], 0, 0, 0);
        acc[0][1] = __builtin_amdgcn_mfma_f32_16x16x32_bf16(a0, b1, acc[0][1], 0, 0, 0);
        acc[0][2] = __builtin_amdgcn_mfma_f32_16x16x32_bf16(a0, b2, acc[0][2], 0, 0, 0);
        acc[0][3] = __builtin_amdgcn_mfma_f32_16x16x32_bf16(a0, b3, acc[0][3], 0, 0, 0);
        acc[1][0] = __builtin_amdgcn_mfma_f32_16x16x32_bf16(a1, b0, acc[1][0], 0, 0, 0);
        acc[1][1] = __builtin_amdgcn_mfma_f32_16x16x32_bf16(a1, b1, acc[1][1], 0, 0, 0);
        acc[1][2] = __builtin_amdgcn_mfma_f32_16x16x32_bf16(a1, b2, acc[1][2], 0, 0, 0);
        acc[1][3] = __builtin_amdgcn_mfma_f32_16x16x32_bf16(a1, b3, acc[1][3], 0, 0, 0);
        acc[2][0] = __builtin_amdgcn_mfma_f32_16x16x32_bf16(a2, b0, acc[2][0], 0, 0, 0);
        acc[2][1] = __builtin_amdgcn_mfma_f32_16x16x32_bf16(a2, b1, acc[2][1], 0, 0, 0);
        acc[2][2] = __builtin_amdgcn_mfma_f32_16x16x32_bf16(a2, b2, acc[2][2], 0, 0, 0);
        acc[2][3] = __builtin_amdgcn_mfma_f32_16x16x32_bf16(a2, b3, acc[2][3], 0, 0, 0);
        acc[3][0] = __builtin_amdgcn_mfma_f32_16x16x32_bf16(a3, b0, acc[3][0], 0, 0, 0);
        acc[3][1] = __builtin_amdgcn_mfma_f32_16x16x32_bf16(a3, b1, acc[3][1], 0, 0, 0);
        acc[3][2] = __builtin_amdgcn_mfma_f32_16x16x32_bf16(a3, b2, acc[3][2], 0, 0, 0);
        acc[3][3] = __builtin_amdgcn_mfma_f32_16x16x32_bf16(a3, b3, acc[3][3], 0, 0, 0);

        __syncthreads();
        cur ^= 1;
    }

    int cRow = (lane >> 4) * 4;
    int cCol = lane & 15;
#pragma unroll
    for (int i = 0; i < 4; ++i) {
#pragma unroll
        for (int j = 0; j < 4; ++j) {
            int col = wave * 64 + j * 16 + cCol;
            if (col >= 200) continue;
#pragma unroll
            for (int r = 0; r < 4; ++r) {
                int row = rowBase + i * 16 + cRow + r;
                if (row < M) {
                    float val = rrelu(acc[i][j][r]);
                    if (outF) outF[(size_t)row * D + col] = val;
                    if (outB) outB[(size_t)row * D + col] = (u16)f2bf(val);
                }
            }
        }
    }
}

// ---- fixup for in-degree-0 nodes: out[v] = rrelu(h[v] @ We) -------------

__global__ void fixup_k(const u16* __restrict__ hb, const float* __restrict__ We,
                        const int* __restrict__ noin, const int* __restrict__ noin_cnt,
                        float* __restrict__ outF, u16* __restrict__ outB) {
    int cnt = *noin_cnt;
    for (int i = blockIdx.x; i < cnt; i += gridDim.x) {
        int v = noin[i];
        int j = threadIdx.x;
        if (j < D) {
            float acc = 0.0f;
            for (int k = 0; k < D; ++k)
                acc += bf2f(hb[(size_t)v * D + k]) * We[(size_t)k * D + j];
            float r = rrelu(acc);
            if (outF) outF[(size_t)v * D + j] = r;
            if (outB) outB[(size_t)v * D + j] = (u16)f2bf(r);
        }
    }
}

extern "C" void kernel_launch(void* const* d_in, const int* in_sizes, int n_in,
                              void* d_out, int out_size, void* d_ws, size_t ws_size,
                              hipStream_t stream) {
    const float* init  = (const float*)d_in[0];
    const float* rel   = (const float*)d_in[1];
    const float* Wn    = (const float*)d_in[2];
    const float* Wl    = (const float*)d_in[3];
    const float* We    = (const float*)d_in[4];
    const float* norm  = (const float*)d_in[5];
    const int* src     = (const int*)d_in[6];
    const int* dst     = (const int*)d_in[7];
    const int* etype   = (const int*)d_in[8];
    const int* node_id = (const int*)d_in[9];
    float* out = (float*)d_out;

    int N = in_sizes[5];
    int E = in_sizes[6];
    size_t NP = (size_t)N + 256;           // row padding for unguarded tile reads

    char* w = (char*)d_ws;
    auto carve = [&](size_t bytes) {
        char* p = w;
        w += (bytes + 255) & ~(size_t)255;
        return p;
    };
    u16* hb0     = (u16*)carve(NP * D * sizeof(u16));       // row N zeroed (dummy)
    u16* hb1     = (u16*)carve(NP * D * sizeof(u16));       // row N zeroed (dummy)
    u16* aggb    = (u16*)carve(NP * D * sizeof(u16));
    u16* relsumb = (u16*)carve((size_t)N * D * sizeof(u16));
    u16* relb    = (u16*)carve((size_t)501 * D * sizeof(u16)); // row 500 zeroed (dummy)
    u16* Bt      = (u16*)carve((size_t)2 * 256 * 416 * sizeof(u16));
    int* cnt     = (int*)carve((size_t)N * sizeof(int));
    u32* epack   = (u32*)carve(((size_t)N * STRIDE + PAD) * sizeof(u32));
    int* noin    = (int*)carve((size_t)N * sizeof(int));
    int* noin_cnt = (int*)carve(sizeof(int));

    (void)hipMemsetAsync(cnt, 0, (size_t)N * sizeof(int), stream);

    int prepN = 2 * 256 * 416;
    int prepB = (prepN + 255) / 256;
    int scatB = (E + 256 * EPT - 1) / (256 * EPT);
    int gathB = (N + 3) / 4;
    front_k<<<scatB + prepB + gathB, 256, 0, stream>>>(
        rel, Wn, Wl, relb, Bt,
        hb0 + (size_t)N * D, hb1 + (size_t)N * D, noin_cnt,
        dst, src, etype, cnt, epack, E,
        init, node_id, hb0, N, prepB, scatB);

    u32 dummy = (u32)N | (500u << 17);
    pad_k<<<(N + 255) / 256, 256, 0, stream>>>(cnt, epack, dummy, noin, noin_cnt, N);

    int gemmBlocks = (N + 63) / 64;

    // layer 0 (fused relsum): bf16 output only
    gagg0_k<<<(N + 7) / 8, 256, 0, stream>>>(hb0, relb, epack, cnt, norm,
                                             aggb, relsumb, N, dummy);
    gemm_k<<<gemmBlocks, 256, 0, stream>>>(aggb, hb0, Bt, nullptr, hb1, N);
    fixup_k<<<8, 256, 0, stream>>>(hb0, We, noin, noin_cnt, nullptr, hb1);

    // layer 1: fp32 output to d_out
    gagg1_k<<<(N + 7) / 8, 256, 0, stream>>>(hb1, epack, cnt, norm,
                                             relsumb, aggb, N, dummy);
    gemm_k<<<gemmBlocks, 256, 0, stream>>>(aggb, hb1, Bt + 256 * 416, out, nullptr, N);
    fixup_k<<<8, 256, 0, stream>>>(hb1, We + D * D, noin, noin_cnt, out, nullptr);
}

// Round 9
// 344.790 us; speedup vs baseline: 1.0554x; 1.0554x over previous
//
#include <hip/hip_runtime.h>

#define D 200
#define RRELU_SLOPE 0.22916666666666666f
#define STRIDE 96              // padded per-node edge capacity (P[deg>96] ~ 1e-41)
#define PAD 8                  // edge-loop round size
#define EPT 8                  // edges per scatter thread (ILP)

typedef unsigned short u16;
typedef unsigned int u32;

using bf16x8 = __attribute__((ext_vector_type(8))) short;
using f32x4  = __attribute__((ext_vector_type(4))) float;
using f32x2  = __attribute__((ext_vector_type(2))) float;

__device__ __forceinline__ float rrelu(float x) {
    return x >= 0.0f ? x : x * RRELU_SLOPE;
}
__device__ __forceinline__ float bf2f(u32 u) {
    union { u32 i; float f; } c; c.i = u << 16; return c.f;
}
__device__ __forceinline__ u32 f2bf(float f) {
    union { float f; u32 i; } c; c.f = f;
    return (c.i + 0x7fffu + ((c.i >> 16) & 1u)) >> 16;
}
__device__ __forceinline__ u32 pack2(float x, float y) {
    return f2bf(x) | (f2bf(y) << 16);
}
__device__ __forceinline__ void gll16(const void* g, void* l) {
    __builtin_amdgcn_global_load_lds((const __attribute__((address_space(1))) void*)g,
                                     (__attribute__((address_space(3))) void*)l,
                                     16, 0, 0);
}

// unpack one u32 (2 bf16 = adjacent channels) and packed-accumulate into f32x2
// (compiler emits v_pk_add_f32 on gfx950).
__device__ __forceinline__ void accw(u32 w, f32x2& acc) {
    union { u32 i; float f; } lo, hi;
    lo.i = w << 16;
    hi.i = w & 0xffff0000u;
    f32x2 t; t[0] = lo.f; t[1] = hi.f;
    acc += t;
}
// unpack uint4 (8 bf16) into 4 packed accumulators
__device__ __forceinline__ void accq(uint4 q, f32x2* a) {
    accw(q.x, a[0]); accw(q.y, a[1]); accw(q.z, a[2]); accw(q.w, a[3]);
}

// ---- fused front kernel: prep (relb/Bt/dummies) + scatter + h0 gather ----
// (exact R7 configuration: prep first, EPT=8 scatter with normal stores)

__global__ void front_k(const float* __restrict__ rel, const float* __restrict__ Wn,
                        const float* __restrict__ Wl, u16* __restrict__ relb,
                        u16* __restrict__ Bt, u16* __restrict__ hb0d,
                        u16* __restrict__ hb1d, int* __restrict__ noin_cnt,
                        const int* __restrict__ dst, const int* __restrict__ src,
                        const int* __restrict__ etype, int* __restrict__ cnt,
                        u32* __restrict__ ep, int E,
                        const float* __restrict__ init, const int* __restrict__ nid,
                        u16* __restrict__ hb, int N,
                        int prepB, int scatB) {
    int b = blockIdx.x;
    if (b < prepB) {
        int i = b * blockDim.x + threadIdx.x;
        if (i == 0) *noin_cnt = 0;
        if (i < 200) { hb0d[i] = 0; hb1d[i] = 0; }
        if (i < 100200) relb[i] = (i < 100000) ? (u16)f2bf(rel[i]) : (u16)0;
        if (i < 2 * 256 * 416) {
            int l = i / (256 * 416);
            int rem = i % (256 * 416);
            int c = rem / 416;
            int k = rem % 416;
            float v = 0.0f;
            if (c < 200 && k < 400)
                v = (k < 200) ? Wn[(size_t)l * 40000 + k * 200 + c]
                              : Wl[(size_t)l * 40000 + (k - 200) * 200 + c];
            Bt[i] = (u16)f2bf(v);
        }
    } else if (b < prepB + scatB) {
        int base = ((b - prepB) * blockDim.x + threadIdx.x) * EPT;
        if (base + EPT <= E) {
            int4 d0 = *(const int4*)(dst + base);
            int4 d1 = *(const int4*)(dst + base + 4);
            int4 s0 = *(const int4*)(src + base);
            int4 s1 = *(const int4*)(src + base + 4);
            int4 t0 = *(const int4*)(etype + base);
            int4 t1 = *(const int4*)(etype + base + 4);
            int dd[8] = {d0.x, d0.y, d0.z, d0.w, d1.x, d1.y, d1.z, d1.w};
            int ss[8] = {s0.x, s0.y, s0.z, s0.w, s1.x, s1.y, s1.z, s1.w};
            int tt[8] = {t0.x, t0.y, t0.z, t0.w, t1.x, t1.y, t1.z, t1.w};
            int cc[8];
#pragma unroll
            for (int j = 0; j < 8; ++j) cc[j] = atomicAdd(&cnt[dd[j]], 1);
#pragma unroll
            for (int j = 0; j < 8; ++j)
                if (cc[j] < STRIDE)
                    ep[(size_t)dd[j] * STRIDE + cc[j]] = (u32)ss[j] | ((u32)tt[j] << 17);
        } else {
            for (int j = 0; j < EPT; ++j) {
                int e = base + j;
                if (e < E) {
                    int d = dst[e];
                    int c = atomicAdd(&cnt[d], 1);
                    if (c < STRIDE)
                        ep[(size_t)d * STRIDE + c] = (u32)src[e] | ((u32)etype[e] << 17);
                }
            }
        }
    } else {
        int lane = threadIdx.x & 63;
        int v = (b - prepB - scatB) * 4 + (threadIdx.x >> 6);
        if (v >= N || lane >= 50) return;
        float4 f = *(const float4*)(init + (size_t)nid[v] * D + lane * 4);
        uint2 o;
        o.x = pack2(f.x, f.y);
        o.y = pack2(f.z, f.w);
        *(uint2*)(hb + (size_t)v * D + lane * 4) = o;
    }
}

// ---- layer-0 gather: aggb = bf16((Σh + Σrel)*norm), relsumb = bf16(Σrel)
// Two nodes per wave (half-wave each, 25 lanes x uint4). Depth-1 pipeline.
// Tail masking replaces pad_k's dummy fill (idx<c select; dummy rows zeroed).
// Also builds the noin list (half-wave leader, c==0) for the fixups.

__global__ __launch_bounds__(256) void gagg0_k(
        const u16* __restrict__ hb, const u16* __restrict__ relb,
        const u32* __restrict__ ep, const int* __restrict__ cnt,
        const float* __restrict__ norm,
        u16* __restrict__ aggb, u16* __restrict__ relsumb,
        int* __restrict__ noin, int* __restrict__ noin_cnt, int N, u32 dummy) {
    int lane = threadIdx.x & 63;
    int wave = threadIdx.x >> 6;
    int li = lane & 31;
    int v = blockIdx.x * 8 + wave * 2 + (lane >> 5);
    if (v >= N || li >= 25) return;
    size_t lo = (size_t)li * 8;
    const u16* hbL = hb + lo;
    const u16* rbL = relb + lo;
    int c = cnt[v];
    if (c > STRIDE) c = STRIDE;
    if (li == 0 && c == 0) noin[atomicAdd(noin_cnt, 1)] = v;
    int rv = (c + PAD - 1) >> 3;
    const u32* pp = ep + (size_t)v * STRIDE;
    f32x2 a[4] = {}, rr[4] = {};
    u32 p[8];
    uint4 qh[8];
#pragma unroll
    for (int j = 0; j < 8; ++j) p[j] = (j < c) ? pp[j] : dummy;
#pragma unroll
    for (int j = 0; j < 8; ++j)
        qh[j] = *(const uint4*)(hbL + (size_t)(p[j] & 0x1FFFFu) * D);
    for (int r = 0; r < rv; ++r) {
        int nb = (r + 1) * 8;
        u32 pn[8];
#pragma unroll
        for (int j = 0; j < 8; ++j)
            pn[j] = (nb + j < c) ? pp[nb + j] : dummy;
        uint4 qr[8];
#pragma unroll
        for (int j = 0; j < 8; ++j)
            qr[j] = *(const uint4*)(rbL + (size_t)((p[j] >> 17) & 0x3FFu) * D);
#pragma unroll
        for (int j = 0; j < 8; ++j) accq(qh[j], a);
#pragma unroll
        for (int j = 0; j < 8; ++j)
            qh[j] = *(const uint4*)(hbL + (size_t)(pn[j] & 0x1FFFFu) * D);
#pragma unroll
        for (int j = 0; j < 8; ++j) accq(qr[j], rr);
#pragma unroll
        for (int j = 0; j < 8; ++j) p[j] = pn[j];
    }
    uint4 rs;
    rs.x = pack2(rr[0][0], rr[0][1]); rs.y = pack2(rr[1][0], rr[1][1]);
    rs.z = pack2(rr[2][0], rr[2][1]); rs.w = pack2(rr[3][0], rr[3][1]);
    *(uint4*)(relsumb + (size_t)v * D + lo) = rs;
    float nv = norm[v];
    uint4 o;
    o.x = pack2((a[0][0] + rr[0][0]) * nv, (a[0][1] + rr[0][1]) * nv);
    o.y = pack2((a[1][0] + rr[1][0]) * nv, (a[1][1] + rr[1][1]) * nv);
    o.z = pack2((a[2][0] + rr[2][0]) * nv, (a[2][1] + rr[2][1]) * nv);
    o.w = pack2((a[3][0] + rr[3][0]) * nv, (a[3][1] + rr[3][1]) * nv);
    *(uint4*)(aggb + (size_t)v * D + lo) = o;
}

// ---- layer-1 gather: aggb = bf16((Σh + relsumb)*norm), tail-masked ------

__global__ __launch_bounds__(256) void gagg1_k(
        const u16* __restrict__ hb, const u32* __restrict__ ep,
        const int* __restrict__ cnt, const float* __restrict__ norm,
        const u16* __restrict__ addb, u16* __restrict__ outb, int N, u32 dummy) {
    int lane = threadIdx.x & 63;
    int wave = threadIdx.x >> 6;
    int li = lane & 31;
    int v = blockIdx.x * 8 + wave * 2 + (lane >> 5);
    if (v >= N || li >= 25) return;
    size_t lo = (size_t)li * 8;
    const u16* hbL = hb + lo;
    int c = cnt[v];
    if (c > STRIDE) c = STRIDE;
    int rv = (c + PAD - 1) >> 3;
    const u32* pp = ep + (size_t)v * STRIDE;
    f32x2 a[4] = {};
    u32 p[8];
    uint4 qh[8];
#pragma unroll
    for (int j = 0; j < 8; ++j) p[j] = (j < c) ? pp[j] : dummy;
#pragma unroll
    for (int j = 0; j < 8; ++j)
        qh[j] = *(const uint4*)(hbL + (size_t)(p[j] & 0x1FFFFu) * D);
    for (int r = 0; r < rv; ++r) {
        int nb = (r + 1) * 8;
        u32 pn[8];
#pragma unroll
        for (int j = 0; j < 8; ++j)
            pn[j] = (nb + j < c) ? pp[nb + j] : dummy;
#pragma unroll
        for (int j = 0; j < 8; ++j) accq(qh[j], a);
#pragma unroll
        for (int j = 0; j < 8; ++j)
            qh[j] = *(const uint4*)(hbL + (size_t)(pn[j] & 0x1FFFFu) * D);
#pragma unroll
        for (int j = 0; j < 8; ++j) p[j] = pn[j];
    }
    {
        uint4 q = *(const uint4*)(addb + (size_t)v * D + lo);
        accq(q, a);
    }
    float nv = norm[v];
    uint4 o;
    o.x = pack2(a[0][0] * nv, a[0][1] * nv);
    o.y = pack2(a[1][0] * nv, a[1][1] * nv);
    o.z = pack2(a[2][0] * nv, a[2][1] * nv);
    o.w = pack2(a[3][0] * nv, a[3][1] * nv);
    *(uint4*)(outb + (size_t)v * D + lo) = o;
}

// ---- MFMA GEMM: out = rrelu([aggb | hb] @ Bt^T) -------------------------
// BM=64 x BN=256 (all cols in one pass; A read once). Double-buffered LDS,
// 2-phase pipeline: STAGE(t+1) issued BEFORE compute(t); ONE barrier/K-step.

__global__ __launch_bounds__(256) void gemm_k(
        const u16* __restrict__ Aagg, const u16* __restrict__ Ah,
        const u16* __restrict__ Bt,
        float* __restrict__ outF, u16* __restrict__ outB, int M) {
    __shared__ __align__(16) u16 As[2][64 * 32];     // 2 x 4 KB
    __shared__ __align__(16) u16 Bs[2][256 * 32];    // 2 x 16 KB
    int tid = threadIdx.x;
    int lane = tid & 63;
    int wave = tid >> 6;
    int rowBase = blockIdx.x * 64;
    int m = lane & 15;
    int kq = (lane >> 4) * 8;

    int srow = tid >> 2;            // 0..63 (A-row / B-col within chunk)
    int kg = (tid & 3) * 8;
    size_t aRow = (size_t)(rowBase + srow);

    f32x4 acc[4][4] = {};

    auto stage = [&](int buf, int k0) {
        int k = k0 + kg;
        const u16* gA = (k < 200) ? Aagg + aRow * D + k
                                  : Ah + aRow * D + (k - 200);
        gll16(gA, &As[buf][0] + wave * 512);
#pragma unroll
        for (int p = 0; p < 4; ++p) {
            const u16* gB = Bt + (size_t)(p * 64 + srow) * 416 + k;
            gll16(gB, &Bs[buf][0] + p * 2048 + wave * 512);
        }
    };

    stage(0, 0);
    __syncthreads();

    int cur = 0;
    for (int t = 0; t < 13; ++t) {
        if (t < 12) stage(cur ^ 1, (t + 1) * 32);   // prefetch next tile

        const u16* A = &As[cur][0];
        const u16* B = &Bs[cur][0];
        bf16x8 a0 = *(const bf16x8*)(A + (m) * 32 + kq);
        bf16x8 a1 = *(const bf16x8*)(A + (16 + m) * 32 + kq);
        bf16x8 a2 = *(const bf16x8*)(A + (32 + m) * 32 + kq);
        bf16x8 a3 = *(const bf16x8*)(A + (48 + m) * 32 + kq);
        int wc = wave * 64;
        bf16x8 b0 = *(const bf16x8*)(B + (wc + m) * 32 + kq);
        bf16x8 b1 = *(const bf16x8*)(B + (wc + 16 + m) * 32 + kq);
        bf16x8 b2 = *(const bf16x8*)(B + (wc + 32 + m) * 32 + kq);
        bf16x8 b3 = *(const bf16x8*)(B + (wc + 48 + m) * 32 + kq);
        acc[0][0] = __builtin_amdgcn_mfma_f32_16x16x32_bf16(a0, b0, acc[0][0], 0, 0, 0);
        acc[0][1] = __builtin_amdgcn_mfma_f32_16x16x32_bf16(a0, b1, acc[0][1], 0, 0, 0);
        acc[0][2] = __builtin_amdgcn_mfma_f32_16x16x32_bf16(a0, b2, acc[0][2], 0, 0, 0);
        acc[0][3] = __builtin_amdgcn_mfma_f32_16x16x32_bf16(a0, b3, acc[0][3], 0, 0, 0);
        acc[1][0] = __builtin_amdgcn_mfma_f32_16x16x32_bf16(a1, b0, acc[1][0], 0, 0, 0);
        acc[1][1] = __builtin_amdgcn_mfma_f32_16x16x32_bf16(a1, b1, acc[1][1], 0, 0, 0);
        acc[1][2] = __builtin_amdgcn_mfma_f32_16x16x32_bf16(a1, b2, acc[1][2], 0, 0, 0);
        acc[1][3] = __builtin_amdgcn_mfma_f32_16x16x32_bf16(a1, b3, acc[1][3], 0, 0, 0);
        acc[2][0] = __builtin_amdgcn_mfma_f32_16x16x32_bf16(a2, b0, acc[2][0], 0, 0, 0);
        acc[2][1] = __builtin_amdgcn_mfma_f32_16x16x32_bf16(a2, b1, acc[2][1], 0, 0, 0);
        acc[2][2] = __builtin_amdgcn_mfma_f32_16x16x32_bf16(a2, b2, acc[2][2], 0, 0, 0);
        acc[2][3] = __builtin_amdgcn_mfma_f32_16x16x32_bf16(a2, b3, acc[2][3], 0, 0, 0);
        acc[3][0] = __builtin_amdgcn_mfma_f32_16x16x32_bf16(a3, b0, acc[3][0], 0, 0, 0);
        acc[3][1] = __builtin_amdgcn_mfma_f32_16x16x32_bf16(a3, b1, acc[3][1], 0, 0, 0);
        acc[3][2] = __builtin_amdgcn_mfma_f32_16x16x32_bf16(a3, b2, acc[3][2], 0, 0, 0);
        acc[3][3] = __builtin_amdgcn_mfma_f32_16x16x32_bf16(a3, b3, acc[3][3], 0, 0, 0);

        __syncthreads();
        cur ^= 1;
    }

    int cRow = (lane >> 4) * 4;
    int cCol = lane & 15;
#pragma unroll
    for (int i = 0; i < 4; ++i) {
#pragma unroll
        for (int j = 0; j < 4; ++j) {
            int col = wave * 64 + j * 16 + cCol;
            if (col >= 200) continue;
#pragma unroll
            for (int r = 0; r < 4; ++r) {
                int row = rowBase + i * 16 + cRow + r;
                if (row < M) {
                    float val = rrelu(acc[i][j][r]);
                    if (outF) outF[(size_t)row * D + col] = val;
                    if (outB) outB[(size_t)row * D + col] = (u16)f2bf(val);
                }
            }
        }
    }
}

// ---- fixup for in-degree-0 nodes: out[v] = rrelu(h[v] @ We) -------------

__global__ void fixup_k(const u16* __restrict__ hb, const float* __restrict__ We,
                        const int* __restrict__ noin, const int* __restrict__ noin_cnt,
                        float* __restrict__ outF, u16* __restrict__ outB) {
    int cnt = *noin_cnt;
    for (int i = blockIdx.x; i < cnt; i += gridDim.x) {
        int v = noin[i];
        int j = threadIdx.x;
        if (j < D) {
            float acc = 0.0f;
            for (int k = 0; k < D; ++k)
                acc += bf2f(hb[(size_t)v * D + k]) * We[(size_t)k * D + j];
            float r = rrelu(acc);
            if (outF) outF[(size_t)v * D + j] = r;
            if (outB) outB[(size_t)v * D + j] = (u16)f2bf(r);
        }
    }
}

extern "C" void kernel_launch(void* const* d_in, const int* in_sizes, int n_in,
                              void* d_out, int out_size, void* d_ws, size_t ws_size,
                              hipStream_t stream) {
    const float* init  = (const float*)d_in[0];
    const float* rel   = (const float*)d_in[1];
    const float* Wn    = (const float*)d_in[2];
    const float* Wl    = (const float*)d_in[3];
    const float* We    = (const float*)d_in[4];
    const float* norm  = (const float*)d_in[5];
    const int* src     = (const int*)d_in[6];
    const int* dst     = (const int*)d_in[7];
    const int* etype   = (const int*)d_in[8];
    const int* node_id = (const int*)d_in[9];
    float* out = (float*)d_out;

    int N = in_sizes[5];
    int E = in_sizes[6];
    size_t NP = (size_t)N + 256;           // row padding for unguarded tile reads

    char* w = (char*)d_ws;
    auto carve = [&](size_t bytes) {
        char* p = w;
        w += (bytes + 255) & ~(size_t)255;
        return p;
    };
    u16* hb0     = (u16*)carve(NP * D * sizeof(u16));       // row N zeroed (dummy)
    u16* hb1     = (u16*)carve(NP * D * sizeof(u16));       // row N zeroed (dummy)
    u16* aggb    = (u16*)carve(NP * D * sizeof(u16));
    u16* relsumb = (u16*)carve((size_t)N * D * sizeof(u16));
    u16* relb    = (u16*)carve((size_t)501 * D * sizeof(u16)); // row 500 zeroed (dummy)
    u16* Bt      = (u16*)carve((size_t)2 * 256 * 416 * sizeof(u16));
    int* cnt     = (int*)carve((size_t)N * sizeof(int));
    u32* epack   = (u32*)carve(((size_t)N * STRIDE + PAD) * sizeof(u32));
    int* noin    = (int*)carve((size_t)N * sizeof(int));
    int* noin_cnt = (int*)carve(sizeof(int));

    (void)hipMemsetAsync(cnt, 0, (size_t)N * sizeof(int), stream);

    int prepN = 2 * 256 * 416;
    int prepB = (prepN + 255) / 256;
    int scatB = (E + 256 * EPT - 1) / (256 * EPT);
    int gathB = (N + 3) / 4;
    front_k<<<prepB + scatB + gathB, 256, 0, stream>>>(
        rel, Wn, Wl, relb, Bt,
        hb0 + (size_t)N * D, hb1 + (size_t)N * D, noin_cnt,
        dst, src, etype, cnt, epack, E,
        init, node_id, hb0, N, prepB, scatB);

    u32 dummy = (u32)N | (500u << 17);
    int gemmBlocks = (N + 63) / 64;

    // layer 0 (fused relsum + noin build): bf16 output only
    gagg0_k<<<(N + 7) / 8, 256, 0, stream>>>(hb0, relb, epack, cnt, norm,
                                             aggb, relsumb, noin, noin_cnt,
                                             N, dummy);
    gemm_k<<<gemmBlocks, 256, 0, stream>>>(aggb, hb0, Bt, nullptr, hb1, N);
    fixup_k<<<8, 256, 0, stream>>>(hb0, We, noin, noin_cnt, nullptr, hb1);

    // layer 1: fp32 output to d_out
    gagg1_k<<<(N + 7) / 8, 256, 0, stream>>>(hb1, epack, cnt, norm,
                                             relsumb, aggb, N, dummy);
    gemm_k<<<gemmBlocks, 256, 0, stream>>>(aggb, hb1, Bt + 256 * 416, out, nullptr, N);
    fixup_k<<<8, 256, 0, stream>>>(hb1, We + D * D, noin, noin_cnt, out, nullptr);
}